// Round 3
// baseline (998.011 us; speedup 1.0000x reference)
//
#include <hip/hip_runtime.h>

#define NTOK 49
#define CDIM 256
#define NWIN 4096

typedef short  s8v  __attribute__((ext_vector_type(8)));
typedef float  v4f  __attribute__((ext_vector_type(4)));

__device__ __forceinline__ unsigned short f2b(float f){
  union { float f; unsigned u; } v; v.f = f;
  unsigned u = v.u;
  return (unsigned short)((u + 0x7fffu + ((u >> 16) & 1u)) >> 16);
}

// Repack a row-major f32 weight matrix [256][ncols] into bf16 MFMA B-fragment order.
// frag = ntile*8 + ks ; lane holds B[k = ks*32 + (lane>>4)*8 + j][n = ntile*16 + (lane&15)]
// stored at packed[(frag*64 + lane)*8 + j]  -> coalesced 16B/lane loads in the main kernel.
__global__ void repack_b(const float* __restrict__ w,
                         unsigned short* __restrict__ packed,
                         int ncols, int nfrag){
  int t = blockIdx.x * 256 + threadIdx.x;
  int frag = t >> 6;
  if (frag >= nfrag) return;
  int lane  = t & 63;
  int ntile = frag >> 3, ks = frag & 7;
  int n  = ntile * 16 + (lane & 15);
  int k0 = ks * 32 + (lane >> 4) * 8;
  unsigned short tmp[8];
#pragma unroll
  for (int j = 0; j < 8; ++j) tmp[j] = f2b(w[(size_t)(k0 + j) * ncols + n]);
  *(s8v*)(packed + (size_t)t * 8) = *(s8v*)tmp;
}

// LDS layout (bytes):
//  [0,      5408)  bias table as f32       (169*8)
//  [5408,  39200)  x / a_out bf16, 64 rows x stride 264 (rows 49-63 zeroed)
//  [39200, 138528) qkv bf16, 64 rows x stride 776 (q:0-255,k:256-511,v:512-767)
//  [138528,147744) P bf16, 64 rows x stride 72
#define OFF_XA  5408
#define OFF_QKV 39200
#define OFF_P   138528
#define LDS_TOTAL 147744

__global__ __launch_bounds__(256, 1) void wattn_main(
    const float* __restrict__ xg,
    const float* __restrict__ bqkv,
    const float* __restrict__ bproj,
    const float* __restrict__ btab,
    const unsigned short* __restrict__ pwq,
    const unsigned short* __restrict__ pwp,
    float* __restrict__ outg)
{
  extern __shared__ char smem[];
  float*          bias_s = (float*)smem;
  unsigned short* xa_s   = (unsigned short*)(smem + OFF_XA);
  unsigned short* qkv_s  = (unsigned short*)(smem + OFF_QKV);
  unsigned short* p_s    = (unsigned short*)(smem + OFF_P);

  const int tid  = threadIdx.x;
  const int wave = tid >> 6;
  const int lane = tid & 63;
  const int quad = lane >> 4;
  const int c16  = lane & 15;
  const int b    = blockIdx.x;
  const size_t xbase = (size_t)b * (NTOK * CDIM);

  // ---- Phase 1: zero ALL readable LDS, stage bias table + x window (f32 -> bf16) ----
  {
    s8v z = {};
    for (int i = tid; i < 64 * 97; i += 256){            // full qkv
      int r = i / 97, c = i - r * 97;
      *(s8v*)(qkv_s + r * 776 + c * 8) = z;
    }
    for (int i = tid; i < 15 * 33; i += 256){            // xa pad rows 49-63
      int r = 49 + i / 33, c = i % 33;
      *(s8v*)(xa_s + r * 264 + c * 8) = z;
    }
    for (int i = tid; i < 64 * 9; i += 256){             // full P
      int r = i / 9, c = i - r * 9;
      *(s8v*)(p_s + r * 72 + c * 8) = z;
    }
  }
  for (int i = tid; i < 169 * 8; i += 256) bias_s[i] = btab[i];

  {
    const float4* xg4 = (const float4*)(xg + xbase);     // block base is 16B-aligned (49*256*4 per block)
    for (int i = tid; i < NTOK * 64; i += 256){
      int row = i >> 6, c4 = i & 63;
      float4 v = xg4[row * 64 + c4];
      unsigned short t[4] = { f2b(v.x), f2b(v.y), f2b(v.z), f2b(v.w) };
      *(unsigned long long*)(xa_s + row * 264 + c4 * 4) = *(unsigned long long*)t;
    }
  }
  __syncthreads();

  // ---- Phase 2: qkv = x @ Wqkv + b_qkv   (wave covers cols [wave*192, wave*192+192)) ----
  for (int chunk = 0; chunk < 3; ++chunk){
    v4f acc[4][4];
#pragma unroll
    for (int mt = 0; mt < 4; ++mt)
#pragma unroll
      for (int nt = 0; nt < 4; ++nt) acc[mt][nt] = (v4f){0.f, 0.f, 0.f, 0.f};
#pragma unroll
    for (int ks = 0; ks < 8; ++ks){
      s8v a[4], bb[4];
#pragma unroll
      for (int mt = 0; mt < 4; ++mt)
        a[mt] = *(const s8v*)(xa_s + (mt * 16 + c16) * 264 + ks * 32 + quad * 8);
#pragma unroll
      for (int nt = 0; nt < 4; ++nt){
        int ntg = wave * 12 + chunk * 4 + nt;
        bb[nt] = *(const s8v*)(pwq + ((size_t)(ntg * 8 + ks) * 64 + lane) * 8);
      }
#pragma unroll
      for (int mt = 0; mt < 4; ++mt)
#pragma unroll
        for (int nt = 0; nt < 4; ++nt)
          acc[mt][nt] = __builtin_amdgcn_mfma_f32_16x16x32_bf16(a[mt], bb[nt], acc[mt][nt], 0, 0, 0);
    }
#pragma unroll
    for (int nt = 0; nt < 4; ++nt){
      int col = wave * 192 + chunk * 64 + nt * 16 + c16;
      float bq = bqkv[col];
#pragma unroll
      for (int mt = 0; mt < 4; ++mt)
#pragma unroll
        for (int reg = 0; reg < 4; ++reg){
          int row = mt * 16 + quad * 4 + reg;
          if (row < NTOK) qkv_s[row * 776 + col] = f2b(acc[mt][nt][reg] + bq);
        }
    }
  }
  __syncthreads();

  // ---- Phase 3: attention. wave owns m-tile = wave (rows wave*16..wave*16+15) ----
  const float scale = 0.1767766952966369f;  // 32^-0.5
  const int mt = wave;
  const int rbase = mt * 16 + quad * 4;
  int rh_[4], rw_[4];
#pragma unroll
  for (int reg = 0; reg < 4; ++reg){
    int rr = rbase + reg; rh_[reg] = rr / 7; rw_[reg] = rr - rh_[reg] * 7;
  }

  for (int h = 0; h < 8; ++h){
    // S = (q*scale) @ k^T  : one K-step (hd=32)
    s8v aq = *(const s8v*)(qkv_s + (mt * 16 + c16) * 776 + h * 32 + quad * 8);
    v4f s[4];
#pragma unroll
    for (int nt = 0; nt < 4; ++nt){
      s8v bk = *(const s8v*)(qkv_s + (nt * 16 + c16) * 776 + 256 + h * 32 + quad * 8);
      v4f z = (v4f){0.f, 0.f, 0.f, 0.f};
      s[nt] = __builtin_amdgcn_mfma_f32_16x16x32_bf16(aq, bk, z, 0, 0, 0);
    }
    // bias + mask (C-layout: row = rbase+reg, col = nt*16 + c16). Masked -> -1e38 sentinel.
#pragma unroll
    for (int nt = 0; nt < 4; ++nt){
      int cc = nt * 16 + c16;
      int chh = cc / 7, cww = cc - chh * 7;
#pragma unroll
      for (int reg = 0; reg < 4; ++reg){
        int rr = rbase + reg;
        float val;
        if (rr < NTOK && cc < NTOK)
          val = s[nt][reg] * scale +
                bias_s[((rh_[reg] - chh + 6) * 13 + (rw_[reg] - cww + 6)) * 8 + h];
        else
          val = -1e38f;
        s[nt][reg] = val;
      }
    }
    // row softmax: masked entries contribute exactly 0; no inf/NaN-adjacent math.
#pragma unroll
    for (int reg = 0; reg < 4; ++reg){
      int rr = rbase + reg;
      float m = fmaxf(fmaxf(s[0][reg], s[1][reg]), fmaxf(s[2][reg], s[3][reg]));
      m = fmaxf(m, __shfl_xor(m, 1, 64));
      m = fmaxf(m, __shfl_xor(m, 2, 64));
      m = fmaxf(m, __shfl_xor(m, 4, 64));
      m = fmaxf(m, __shfl_xor(m, 8, 64));
      float sum = 0.f;
      float p[4];
#pragma unroll
      for (int nt = 0; nt < 4; ++nt){
        int cc = nt * 16 + c16;
        p[nt] = (rr < NTOK && cc < NTOK) ? __expf(s[nt][reg] - m) : 0.f;
        sum += p[nt];
      }
      sum += __shfl_xor(sum, 1, 64);
      sum += __shfl_xor(sum, 2, 64);
      sum += __shfl_xor(sum, 4, 64);
      sum += __shfl_xor(sum, 8, 64);
      float inv = (sum > 0.f) ? (1.0f / sum) : 0.f;
#pragma unroll
      for (int nt = 0; nt < 4; ++nt)
        p_s[rr * 72 + nt * 16 + c16] = f2b(p[nt] * inv);
    }
    __syncthreads();   // make P visible / ordered before the PV A-frag loads

    // PV: O = P @ V
    v4f o[2];
    o[0] = (v4f){0.f, 0.f, 0.f, 0.f};
    o[1] = (v4f){0.f, 0.f, 0.f, 0.f};
#pragma unroll
    for (int ks = 0; ks < 2; ++ks){
      s8v ap = *(const s8v*)(p_s + (mt * 16 + c16) * 72 + ks * 32 + quad * 8);
#pragma unroll
      for (int nt = 0; nt < 2; ++nt){
        s8v bv;
#pragma unroll
        for (int j = 0; j < 8; ++j)
          bv[j] = (short)qkv_s[(ks * 32 + quad * 8 + j) * 776 + 512 + h * 32 + nt * 16 + c16];
        o[nt] = __builtin_amdgcn_mfma_f32_16x16x32_bf16(ap, bv, o[nt], 0, 0, 0);
      }
    }
#pragma unroll
    for (int nt = 0; nt < 2; ++nt)
#pragma unroll
      for (int reg = 0; reg < 4; ++reg){
        int rr = rbase + reg;
        if (rr < NTOK) xa_s[rr * 264 + h * 32 + nt * 16 + c16] = f2b(o[nt][reg]);
      }
  }
  __syncthreads();

  // ---- Phase 4: out = a_out @ Wproj + b_proj  (wave covers cols [wave*64, wave*64+64)), f32 store ----
  {
    v4f acc[4][4];
#pragma unroll
    for (int mti = 0; mti < 4; ++mti)
#pragma unroll
      for (int nt = 0; nt < 4; ++nt) acc[mti][nt] = (v4f){0.f, 0.f, 0.f, 0.f};
#pragma unroll
    for (int ks = 0; ks < 8; ++ks){
      s8v a[4], bw[4];
#pragma unroll
      for (int mti = 0; mti < 4; ++mti)
        a[mti] = *(const s8v*)(xa_s + (mti * 16 + c16) * 264 + ks * 32 + quad * 8);
#pragma unroll
      for (int nt = 0; nt < 4; ++nt){
        int ntg = wave * 4 + nt;
        bw[nt] = *(const s8v*)(pwp + ((size_t)(ntg * 8 + ks) * 64 + lane) * 8);
      }
#pragma unroll
      for (int mti = 0; mti < 4; ++mti)
#pragma unroll
        for (int nt = 0; nt < 4; ++nt)
          acc[mti][nt] = __builtin_amdgcn_mfma_f32_16x16x32_bf16(a[mti], bw[nt], acc[mti][nt], 0, 0, 0);
    }
#pragma unroll
    for (int nt = 0; nt < 4; ++nt){
      int col = wave * 64 + nt * 16 + c16;
      float bp = bproj[col];
#pragma unroll
      for (int mti = 0; mti < 4; ++mti)
#pragma unroll
        for (int reg = 0; reg < 4; ++reg){
          int rr = mti * 16 + quad * 4 + reg;
          if (rr < NTOK)
            outg[xbase + (size_t)rr * 256 + col] = acc[mti][nt][reg] + bp;
        }
    }
  }
}

extern "C" void kernel_launch(void* const* d_in, const int* in_sizes, int n_in,
                              void* d_out, int out_size, void* d_ws, size_t ws_size,
                              hipStream_t stream){
  const float* x     = (const float*)d_in[0];
  const float* wqkv  = (const float*)d_in[1];
  const float* bqkv  = (const float*)d_in[2];
  const float* wproj = (const float*)d_in[3];
  const float* bproj = (const float*)d_in[4];
  const float* btab  = (const float*)d_in[5];
  float* out = (float*)d_out;

  unsigned short* pwq = (unsigned short*)d_ws;          // 48*8*64*8 = 196608 elems (384 KB)
  unsigned short* pwp = pwq + 196608;                   // 16*8*64*8 =  65536 elems (128 KB)

  repack_b<<<96, 256, 0, stream>>>(wqkv, pwq, 768, 384);
  repack_b<<<32, 256, 0, stream>>>(wproj, pwp, 256, 128);

  hipFuncSetAttribute((const void*)wattn_main,
                      hipFuncAttributeMaxDynamicSharedMemorySize, LDS_TOTAL);
  wattn_main<<<NWIN, 256, LDS_TOTAL, stream>>>(x, bqkv, bproj, btab, pwq, pwp, out);
}

// Round 4
// 878.176 us; speedup vs baseline: 1.1365x; 1.1365x over previous
//
#include <hip/hip_runtime.h>

#define NTOK 49
#define NWIN 4096

typedef short  s8v  __attribute__((ext_vector_type(8)));
typedef float  v4f  __attribute__((ext_vector_type(4)));

__device__ __forceinline__ unsigned short f2b(float f){
  union { float f; unsigned u; } v; v.f = f;
  unsigned u = v.u;
  return (unsigned short)((u + 0x7fffu + ((u >> 16) & 1u)) >> 16);
}
__device__ __forceinline__ float b2f(unsigned short u){
  union { float f; unsigned u; } v; v.u = ((unsigned)u) << 16; return v.f;
}

// Repack a row-major f32 weight matrix [256][ncols] into bf16 MFMA B-fragment order.
// frag = ntile*8 + ks ; lane holds B[k = ks*32 + (lane>>4)*8 + j][n = ntile*16 + (lane&15)]
// stored at packed[(frag*64 + lane)*8 + j]  -> coalesced 16B/lane loads in the main kernel.
__global__ void repack_b(const float* __restrict__ w,
                         unsigned short* __restrict__ packed,
                         int ncols, int nfrag){
  int t = blockIdx.x * 256 + threadIdx.x;
  int frag = t >> 6;
  if (frag >= nfrag) return;
  int lane  = t & 63;
  int ntile = frag >> 3, ks = frag & 7;
  int n  = ntile * 16 + (lane & 15);
  int k0 = ks * 32 + (lane >> 4) * 8;
  unsigned short tmp[8];
#pragma unroll
  for (int j = 0; j < 8; ++j) tmp[j] = f2b(w[(size_t)(k0 + j) * ncols + n]);
  *(s8v*)(packed + (size_t)t * 8) = *(s8v*)tmp;
}

// Static LDS ~50.2 KB -> 3 blocks/CU (12 waves/CU).
__global__ __launch_bounds__(256, 3) void wattn_main(
    const float* __restrict__ xg,
    const float* __restrict__ bqkv,
    const float* __restrict__ bproj,
    const float* __restrict__ btab,
    const unsigned short* __restrict__ pwq,
    const unsigned short* __restrict__ pwp,
    float* __restrict__ outg)
{
  __shared__ __align__(16) unsigned short bias_s[169 * 8];   // bf16 bias table
  __shared__ __align__(16) unsigned short aout_s[NTOK * 264];// attention output, bf16
  __shared__ __align__(16) unsigned short qh_s[NTOK * 40];   // per-head Q [token][hd]
  __shared__ __align__(16) unsigned short kh_s[NTOK * 40];   // per-head K [token][hd]
  __shared__ __align__(16) unsigned short vt_s[32 * 72];     // per-head V^T [hd][token], pad tokens zeroed
  __shared__ __align__(16) unsigned short p_s[64 * 72];      // P rows (wave-owned)

  const int tid  = threadIdx.x;
  const int wave = tid >> 6;
  const int lane = tid & 63;
  const int quad = lane >> 4;
  const int c16  = lane & 15;
  const int b    = blockIdx.x;
  const size_t xbase = (size_t)b * (NTOK * 256);

  // ---- Phase 1: bias table (bf16) + zero vt pad tokens 49..63 ----
  for (int i = tid; i < 169 * 8; i += 256) bias_s[i] = f2b(btab[i]);
  for (int i = tid; i < 32 * 15; i += 256){
    int n = i / 15, t = NTOK + i % 15;
    vt_s[n * 72 + t] = 0;
  }

  // ---- x A-fragments straight from global f32 into registers (reused for all heads) ----
  int arow = wave * 16 + c16; if (arow > NTOK - 1) arow = NTOK - 1;   // clamp: dup rows discarded
  const float* xrow = xg + xbase + (size_t)arow * 256;
  s8v a_x[8];
#pragma unroll
  for (int ks = 0; ks < 8; ++ks){
    float4 v0 = *(const float4*)(xrow + ks * 32 + quad * 8);
    float4 v1 = *(const float4*)(xrow + ks * 32 + quad * 8 + 4);
    unsigned short t[8] = { f2b(v0.x), f2b(v0.y), f2b(v0.z), f2b(v0.w),
                            f2b(v1.x), f2b(v1.y), f2b(v1.z), f2b(v1.w) };
    a_x[ks] = *(s8v*)t;
  }

  const int rbase = wave * 16 + quad * 4;
  int rh_[4], rw_[4];
#pragma unroll
  for (int reg = 0; reg < 4; ++reg){
    int rr = rbase + reg; rh_[reg] = rr / 7; rw_[reg] = rr - rh_[reg] * 7;
  }
  const float scale = 0.1767766952966369f;  // 32^-0.5

  // ================= head loop =================
  for (int h = 0; h < 8; ++h){
    // ---- per-head qkv GEMM: own 16-row m-tile x 6 n-tiles (q0 q1 k0 k1 v0 v1) ----
    v4f acc[6];
#pragma unroll
    for (int nt = 0; nt < 6; ++nt) acc[nt] = (v4f){0.f, 0.f, 0.f, 0.f};
#pragma unroll
    for (int ks = 0; ks < 8; ++ks){
#pragma unroll
      for (int nt = 0; nt < 6; ++nt){
        int ntg = (nt >> 1) * 16 + 2 * h + (nt & 1);
        s8v bb = *(const s8v*)(pwq + ((size_t)(ntg * 8 + ks) * 64 + lane) * 8);
        acc[nt] = __builtin_amdgcn_mfma_f32_16x16x32_bf16(a_x[ks], bb, acc[nt], 0, 0, 0);
      }
    }
    // barrier: previous head's consumers (S/PV reads of kh/vt) are done before we overwrite
    __syncthreads();

    // epilogue: q,k row-major [token][hd]; v transposed [hd][token]
#pragma unroll
    for (int nt = 0; nt < 4; ++nt){
      int sec  = nt >> 1;                       // 0 = q, 1 = k
      int wcol = (nt & 1) * 16 + c16;
      float bq = bqkv[sec * 256 + h * 32 + wcol];
      unsigned short* dst = sec ? kh_s : qh_s;
#pragma unroll
      for (int reg = 0; reg < 4; ++reg){
        int row = rbase + reg;
        if (row < NTOK) dst[row * 40 + wcol] = f2b(acc[nt][reg] + bq);
      }
    }
#pragma unroll
    for (int nt = 4; nt < 6; ++nt){
      int vcol = (nt - 4) * 16 + c16;
      float bq = bqkv[512 + h * 32 + vcol];
      unsigned short t[4];
#pragma unroll
      for (int reg = 0; reg < 4; ++reg) t[reg] = f2b(acc[nt][reg] + bq);
      if (rbase + 3 < NTOK)
        *(unsigned long long*)(vt_s + vcol * 72 + rbase) = *(unsigned long long*)t;
      else {
#pragma unroll
        for (int reg = 0; reg < 4; ++reg)
          if (rbase + reg < NTOK) vt_s[vcol * 72 + rbase + reg] = t[reg];
      }
    }
    __syncthreads();   // qkv-head (and, at h=0, bias/vt-pad) visible to all waves

    // ---- S = (Q*scale) K^T + bias, masked softmax (own m-tile rows) ----
    int qrow = wave * 16 + c16; if (qrow > NTOK - 1) qrow = NTOK - 1;
    s8v aq = *(const s8v*)(qh_s + qrow * 40 + quad * 8);
    v4f s[4];
#pragma unroll
    for (int nt = 0; nt < 4; ++nt){
      int tok = nt * 16 + c16; if (tok > NTOK - 1) tok = NTOK - 1;
      s8v bk = *(const s8v*)(kh_s + tok * 40 + quad * 8);
      v4f z = (v4f){0.f, 0.f, 0.f, 0.f};
      s[nt] = __builtin_amdgcn_mfma_f32_16x16x32_bf16(aq, bk, z, 0, 0, 0);
    }
#pragma unroll
    for (int nt = 0; nt < 4; ++nt){
      int cc = nt * 16 + c16;
      int chh = cc / 7, cww = cc - chh * 7;
#pragma unroll
      for (int reg = 0; reg < 4; ++reg){
        int rr = rbase + reg;
        if (rr < NTOK && cc < NTOK)
          s[nt][reg] = s[nt][reg] * scale +
              b2f(bias_s[(((rh_[reg] - chh + 6) * 13 + (rw_[reg] - cww + 6)) << 3) + h]);
        else
          s[nt][reg] = -1e38f;
      }
    }
#pragma unroll
    for (int reg = 0; reg < 4; ++reg){
      int rr = rbase + reg;
      float m = fmaxf(fmaxf(s[0][reg], s[1][reg]), fmaxf(s[2][reg], s[3][reg]));
      m = fmaxf(m, __shfl_xor(m, 1, 64));
      m = fmaxf(m, __shfl_xor(m, 2, 64));
      m = fmaxf(m, __shfl_xor(m, 4, 64));
      m = fmaxf(m, __shfl_xor(m, 8, 64));
      float p[4], sum = 0.f;
#pragma unroll
      for (int nt = 0; nt < 4; ++nt){
        int cc = nt * 16 + c16;
        p[nt] = (rr < NTOK && cc < NTOK) ? __expf(s[nt][reg] - m) : 0.f;
        sum += p[nt];
      }
      sum += __shfl_xor(sum, 1, 64);
      sum += __shfl_xor(sum, 2, 64);
      sum += __shfl_xor(sum, 4, 64);
      sum += __shfl_xor(sum, 8, 64);
      float inv = (sum > 0.f) ? (1.0f / sum) : 0.f;
#pragma unroll
      for (int nt = 0; nt < 4; ++nt)
        p_s[rr * 72 + nt * 16 + c16] = f2b(p[nt] * inv);
    }

    // ---- PV (own rows; P written by this wave, V via b128 from vt) ----
    v4f o[2];
    o[0] = (v4f){0.f, 0.f, 0.f, 0.f};
    o[1] = (v4f){0.f, 0.f, 0.f, 0.f};
#pragma unroll
    for (int ks = 0; ks < 2; ++ks){
      s8v ap = *(const s8v*)(p_s + (wave * 16 + c16) * 72 + ks * 32 + quad * 8);
#pragma unroll
      for (int nt = 0; nt < 2; ++nt){
        s8v bv = *(const s8v*)(vt_s + (nt * 16 + c16) * 72 + ks * 32 + quad * 8);
        o[nt] = __builtin_amdgcn_mfma_f32_16x16x32_bf16(ap, bv, o[nt], 0, 0, 0);
      }
    }
#pragma unroll
    for (int nt = 0; nt < 2; ++nt)
#pragma unroll
      for (int reg = 0; reg < 4; ++reg){
        int row = rbase + reg;
        if (row < NTOK) aout_s[row * 264 + h * 32 + nt * 16 + c16] = f2b(o[nt][reg]);
      }
  } // heads
  __syncthreads();   // aout complete across waves

  // ---- Phase 4: out = aout @ Wproj + b_proj (wave covers n-tiles wave*4..wave*4+3) ----
  {
    v4f acc[4][4];
#pragma unroll
    for (int mti = 0; mti < 4; ++mti)
#pragma unroll
      for (int nt = 0; nt < 4; ++nt) acc[mti][nt] = (v4f){0.f, 0.f, 0.f, 0.f};
#pragma unroll
    for (int ks = 0; ks < 8; ++ks){
      s8v a[4], bw[4];
#pragma unroll
      for (int mti = 0; mti < 4; ++mti){
        int r = mti * 16 + c16; if (r > NTOK - 1) r = NTOK - 1;
        a[mti] = *(const s8v*)(aout_s + r * 264 + ks * 32 + quad * 8);
      }
#pragma unroll
      for (int nt = 0; nt < 4; ++nt){
        int ntg = wave * 4 + nt;
        bw[nt] = *(const s8v*)(pwp + ((size_t)(ntg * 8 + ks) * 64 + lane) * 8);
      }
#pragma unroll
      for (int mti = 0; mti < 4; ++mti)
#pragma unroll
        for (int nt = 0; nt < 4; ++nt)
          acc[mti][nt] = __builtin_amdgcn_mfma_f32_16x16x32_bf16(a[mti], bw[nt], acc[mti][nt], 0, 0, 0);
    }
#pragma unroll
    for (int nt = 0; nt < 4; ++nt){
      int col = wave * 64 + nt * 16 + c16;
      float bp = bproj[col];
#pragma unroll
      for (int mti = 0; mti < 4; ++mti)
#pragma unroll
        for (int reg = 0; reg < 4; ++reg){
          int row = mti * 16 + quad * 4 + reg;
          if (row < NTOK)
            outg[xbase + (size_t)row * 256 + col] = acc[mti][nt][reg] + bp;
        }
    }
  }
}

extern "C" void kernel_launch(void* const* d_in, const int* in_sizes, int n_in,
                              void* d_out, int out_size, void* d_ws, size_t ws_size,
                              hipStream_t stream){
  const float* x     = (const float*)d_in[0];
  const float* wqkv  = (const float*)d_in[1];
  const float* bqkv  = (const float*)d_in[2];
  const float* wproj = (const float*)d_in[3];
  const float* bproj = (const float*)d_in[4];
  const float* btab  = (const float*)d_in[5];
  float* out = (float*)d_out;

  unsigned short* pwq = (unsigned short*)d_ws;          // 48*8*64*8 = 196608 elems (384 KB)
  unsigned short* pwp = pwq + 196608;                   // 16*8*64*8 =  65536 elems (128 KB)

  repack_b<<<96, 256, 0, stream>>>(wqkv, pwq, 768, 384);
  repack_b<<<32, 256, 0, stream>>>(wproj, pwp, 256, 128);

  wattn_main<<<NWIN, 256, 0, stream>>>(x, bqkv, bproj, btab, pwq, pwp, out);
}